// Round 2
// baseline (276.318 us; speedup 1.0000x reference)
//
#include <hip/hip_runtime.h>
#include <hip/hip_fp16.h>

#define IN_F 128
#define HID  128
#define NC   10
#define H2P  16     // h2 row stride in HALVES (32 B)
#define NPB  128    // nodes per bin (bin = dst>>7, local = dst&127)
#define NBMAX 784   // max bins (N=100000 -> 782)
#define BCAP 2560   // per-bin edge capacity (mean 2046, +11 sigma)
#define CAPP 2944   // per-bin PADDED csr capacity: BCAP + NPB*3 (each node padded to x4)
#define EPB  4096   // edges per bin-role block (1024 thr x 4) -> 391 blocks
#define LDW  136    // padded LDS row stride in halves (272B -> lane-bank stride 4, ~2-way)

typedef _Float16 f16x8 __attribute__((ext_vector_type(8)));
typedef float f32x4 __attribute__((ext_vector_type(4)));
typedef int int4a __attribute__((ext_vector_type(4), aligned(4)));  // 4B-aligned vec4

__device__ inline __half2 shfl_xor_h2(__half2 v, int mask) {
    int i = __shfl_xor(*reinterpret_cast<int*>(&v), mask, 64);
    return *reinterpret_cast<__half2*>(&i);
}

// ------- k_prep: deg atomics (edge scan) + WT/W2T transposes + sentinels -----
// deg/bcnt zeroed by the preceding memset. Runs before k_work so the GEMM role
// can scale by rsqrt(1+deg) (keeps hsh PRE-SCALED -> agg1 numerics unchanged).
__global__ __launch_bounds__(1024) void k_prep(const int* __restrict__ dst,
                                               int* __restrict__ deg,
                                               const float* __restrict__ W1,
                                               __half* __restrict__ WT,
                                               const float* __restrict__ W2,
                                               float* __restrict__ W2T,
                                               __half* __restrict__ hsh,
                                               __half* __restrict__ h2h,
                                               int E, int N) {
    const int gt = blockIdx.x * 1024 + threadIdx.x;
    const int stride = gridDim.x * 1024;
    for (int i = gt; i < IN_F * HID; i += stride) {
        int k = i >> 7, n = i & 127;
        WT[n * IN_F + k] = __float2half(W1[i]);      // W1[k*HID+n] == W1[i]
    }
    if (blockIdx.x == 0) {
        for (int i = threadIdx.x; i < NC * IN_F; i += 1024)
            W2T[i] = W2[(i & 127) * NC + (i >> 7)];
        if (threadIdx.x < HID) hsh[(size_t)N * HID + threadIdx.x] = __float2half(0.0f);
        if (threadIdx.x < H2P) h2h[(size_t)N * H2P + threadIdx.x] = __float2half(0.0f);
    }
    for (int i = gt; i < E; i += stride) atomicAdd(&deg[dst[i]], 1);
}

// ------- k_work (grid-split): blocks [0,NBG) = GEMM1 tiles, [NBG,..) = binning
// Roles touch disjoint data -> concurrent on the GPU, total ~= max(parts).
__global__ __launch_bounds__(1024, 4) void k_work(const int* __restrict__ src,
                                                  const int* __restrict__ dst,
                                                  int* __restrict__ bcnt,
                                                  unsigned int* __restrict__ binned,
                                                  const float* __restrict__ X,
                                                  const __half* __restrict__ WT,
                                                  const int* __restrict__ deg,
                                                  float* __restrict__ dis,
                                                  __half* __restrict__ hsh,
                                                  int E, int nbin, int N, int NBG) {
    __shared__ __align__(16) char smem[2 * 128 * LDW * 2 + 512];
    const int tid = threadIdx.x;

    if (blockIdx.x >= NBG) {
        // ---------------- binning role (identical math to prior k_bin) ------
        int* hist = (int*)smem;
        int* base = hist + NBMAX;
        int* lcur = base + NBMAX;
        for (int b = tid; b < nbin; b += 1024) { hist[b] = 0; lcur[b] = 0; }
        __syncthreads();

        const int e0 = (blockIdx.x - NBG) * EPB + tid;
        int d[4];
        #pragma unroll
        for (int u = 0; u < 4; u++) {
            int e = e0 + u * 1024;
            d[u] = (e < E) ? dst[e] : -1;
            if (d[u] >= 0) atomicAdd(&hist[d[u] >> 7], 1);
        }
        __syncthreads();
        for (int b = tid; b < nbin; b += 1024) {
            int h = hist[b];
            base[b] = h ? atomicAdd(&bcnt[b], h) : 0;
        }
        __syncthreads();
        #pragma unroll
        for (int u = 0; u < 4; u++) {
            int e = e0 + u * 1024;
            if (e < E) {
                int dd = d[u];
                int b = dd >> 7;
                int s = src[e];
                int o = base[b] + atomicAdd(&lcur[b], 1);
                if (o < BCAP)
                    binned[(size_t)b * BCAP + o] = ((unsigned)(dd & 127) << 17) | (unsigned)s;
            }
        }
        return;
    }

    // ---------------- GEMM role: 128-row tile, 16 waves ----------------------
    _Float16* sX = (_Float16*)smem;                       // [128][LDW]
    _Float16* sW = sX + 128 * LDW;                        // [128][LDW]
    float* sdis  = (float*)(smem + 2 * 128 * LDW * 2);    // [128]
    const int row0 = blockIdx.x * 128;

    {   // stage WT -> sW (16B chunks, conflict-free with LDW pad)
        int n = tid >> 3, c = tid & 7;
        const f16x8* sp = (const f16x8*)(WT + n * IN_F);
        *(f16x8*)(sW + n * LDW + c * 8)       = sp[c];
        *(f16x8*)(sW + n * LDW + (c + 8) * 8) = sp[c + 8];
    }
    {   // stage X tile (fp32 -> fp16)
        int r = tid >> 3;
        int k0 = (tid & 7) * 16;
        int row = row0 + r; if (row >= N) row = N - 1;
        const float* sp = X + (size_t)row * IN_F + k0;
        float4 f0 = *(const float4*)(sp);
        float4 f1 = *(const float4*)(sp + 4);
        float4 f2 = *(const float4*)(sp + 8);
        float4 f3 = *(const float4*)(sp + 12);
        f16x8 h0, h1;
        h0[0] = (_Float16)f0.x; h0[1] = (_Float16)f0.y;
        h0[2] = (_Float16)f0.z; h0[3] = (_Float16)f0.w;
        h0[4] = (_Float16)f1.x; h0[5] = (_Float16)f1.y;
        h0[6] = (_Float16)f1.z; h0[7] = (_Float16)f1.w;
        h1[0] = (_Float16)f2.x; h1[1] = (_Float16)f2.y;
        h1[2] = (_Float16)f2.z; h1[3] = (_Float16)f2.w;
        h1[4] = (_Float16)f3.x; h1[5] = (_Float16)f3.y;
        h1[6] = (_Float16)f3.z; h1[7] = (_Float16)f3.w;
        *(f16x8*)(sX + r * LDW + k0) = h0;
        *(f16x8*)(sX + r * LDW + k0 + 8) = h1;
    }
    if (tid < 128) {   // dis for this tile's rows (deg final after k_prep)
        int row = row0 + tid;
        if (row < N) {
            float dd = rsqrtf(1.0f + (float)deg[row]);
            dis[row] = dd;
            sdis[tid] = dd;
        } else sdis[tid] = 0.0f;
    }
    __syncthreads();

    const int wave = tid >> 6;        // 0..15
    const int sub  = wave >> 2;       // row subtile 0..3 (32 rows each)
    const int nbase = (wave & 3) * 32;
    const int lane = tid & 63;
    const int quad = lane >> 4;
    const int l16 = lane & 15;
    const int rbase = sub * 32;

    f32x4 acc00 = {0,0,0,0}, acc01 = {0,0,0,0}, acc10 = {0,0,0,0}, acc11 = {0,0,0,0};
    #pragma unroll
    for (int kc = 0; kc < 4; kc++) {
        const int koff = kc * 32 + quad * 8;
        f16x8 a0 = *(const f16x8*)(sX + (rbase + l16) * LDW + koff);
        f16x8 a1 = *(const f16x8*)(sX + (rbase + 16 + l16) * LDW + koff);
        f16x8 b0 = *(const f16x8*)(sW + (nbase + l16) * LDW + koff);
        f16x8 b1 = *(const f16x8*)(sW + (nbase + 16 + l16) * LDW + koff);
        acc00 = __builtin_amdgcn_mfma_f32_16x16x32_f16(a0, b0, acc00, 0, 0, 0);
        acc01 = __builtin_amdgcn_mfma_f32_16x16x32_f16(a0, b1, acc01, 0, 0, 0);
        acc10 = __builtin_amdgcn_mfma_f32_16x16x32_f16(a1, b0, acc10, 0, 0, 0);
        acc11 = __builtin_amdgcn_mfma_f32_16x16x32_f16(a1, b1, acc11, 0, 0, 0);
    }
    #pragma unroll
    for (int r = 0; r < 4; r++) {
        {
            int lr = rbase + quad * 4 + r;
            int row = row0 + lr;
            if (row < N) {
                float d = sdis[lr];
                __half* o = hsh + (size_t)row * HID + nbase + l16;
                o[0]  = __float2half(acc00[r] * d);
                o[16] = __float2half(acc01[r] * d);
            }
        }
        {
            int lr = rbase + 16 + quad * 4 + r;
            int row = row0 + lr;
            if (row < N) {
                float d = sdis[lr];
                __half* o = hsh + (size_t)row * HID + nbase + l16;
                o[0]  = __float2half(acc10[r] * d);
                o[16] = __float2half(acc11[r] * d);
            }
        }
    }
}

// ------- k_place: scan cnt4 (from deg, no hist pass) -> rowinfo, scatter csr -
__global__ __launch_bounds__(256) void k_place(const int* __restrict__ bcnt,
                                               const unsigned int* __restrict__ binned,
                                               const int* __restrict__ deg,
                                               int2* __restrict__ rowinfo,
                                               int* __restrict__ csr,
                                               int N) {
    __shared__ int lb[NPB];
    __shared__ int cur[NPB];
    const int b = blockIdx.x;
    const int tid = threadIdx.x;

    int myh = 0, cnt4 = 0;
    if (tid < NPB) {
        int node = b * NPB + tid;
        myh = (node < N) ? deg[node] : 0;
        cnt4 = (myh + 3) & ~3;
        lb[tid] = cnt4;
    }
    __syncthreads();
    #pragma unroll
    for (int off = 1; off < NPB; off <<= 1) {
        int t = (tid < NPB && tid >= off) ? lb[tid - off] : 0;
        __syncthreads();
        if (tid < NPB) lb[tid] += t;
        __syncthreads();
    }
    int ex = 0;
    if (tid < NPB) {
        ex = lb[tid] - cnt4;
        int node = b * NPB + tid;
        if (node < N) rowinfo[node] = make_int2(b * CAPP + ex, cnt4);
        lb[tid] = ex;     // exclusive offsets for scatter
        cur[tid] = 0;
    }
    __syncthreads();
    const int m = min(bcnt[b], BCAP);
    const unsigned int* p = binned + (size_t)b * BCAP;
    for (int i = tid; i < m; i += 256) {
        unsigned v = p[i];
        int dl = v >> 17;
        int r = atomicAdd(&cur[dl], 1);
        csr[b * CAPP + lb[dl] + r] = (int)(v & 0x1FFFF);
    }
    if (tid < NPB) {        // pad tail of each node's list with sentinel N
        for (int k = myh; k < cnt4; k++) csr[b * CAPP + ex + k] = N;
    }
}

// ------- agg1: maskless padded gather (pre-scaled rows) + bias/ReLU + GEMM2 --
// No LDS (W2T read from global, L1-hot), no syncthreads; csr prefetched one
// round ahead so the csr->rows chain overlaps across rounds.
__global__ __launch_bounds__(256) void k_agg1(const __half* __restrict__ hsh,
                                              const int2* __restrict__ rowinfo,
                                              const int* __restrict__ csr,
                                              const float* __restrict__ dis,
                                              const float* __restrict__ b1,
                                              const float* __restrict__ W2T,
                                              __half* __restrict__ h2h,
                                              int N) {
    const int node = blockIdx.x * 4 + (threadIdx.x >> 6);
    if (node >= N) return;
    const int lane = threadIdx.x & 63;
    const int g   = lane >> 4;
    const int l16 = lane & 15;
    const int f0  = l16 * 8;       // 8 halves per lane
    const __half2 hz = __half2half2(__float2half(0.0f));

    const int2 ri = rowinfo[node];
    const int beg = ri.x, end = ri.x + ri.y;
    const float d = dis[node];

    __half2 acc2[4] = {hz, hz, hz, hz};
    if (g == 0) {   // self term (hsh pre-scaled by dis[src])
        float4 r = *(const float4*)(hsh + (size_t)node * HID + f0);
        const __half2* hh = (const __half2*)&r;
        acc2[0] = hh[0]; acc2[1] = hh[1]; acc2[2] = hh[2]; acc2[3] = hh[3];
    }

    int j0 = beg + 4 * g;
    if (j0 < end) {
        int4a cv = *(const int4a*)(csr + j0);
        while (true) {
            const int jn = j0 + 16;
            const bool more = (jn < end);
            int4a cvn = cv;
            if (more) cvn = *(const int4a*)(csr + jn);
            float4 r0 = *(const float4*)(hsh + (size_t)cv[0] * HID + f0);
            float4 r1 = *(const float4*)(hsh + (size_t)cv[1] * HID + f0);
            float4 r2 = *(const float4*)(hsh + (size_t)cv[2] * HID + f0);
            float4 r3 = *(const float4*)(hsh + (size_t)cv[3] * HID + f0);
            const __half2* h0 = (const __half2*)&r0;
            const __half2* h1 = (const __half2*)&r1;
            const __half2* h2 = (const __half2*)&r2;
            const __half2* h3 = (const __half2*)&r3;
            #pragma unroll
            for (int i = 0; i < 4; i++) {
                acc2[i] = __hadd2(acc2[i], h0[i]);
                acc2[i] = __hadd2(acc2[i], h1[i]);
                acc2[i] = __hadd2(acc2[i], h2[i]);
                acc2[i] = __hadd2(acc2[i], h3[i]);
            }
            if (!more) break;
            cv = cvn; j0 = jn;
        }
    }

    // merge the 4 sub-groups, then widen
    #pragma unroll
    for (int i = 0; i < 4; i++) {
        acc2[i] = __hadd2(acc2[i], shfl_xor_h2(acc2[i], 16));
        acc2[i] = __hadd2(acc2[i], shfl_xor_h2(acc2[i], 32));
    }
    float acc[8];
    #pragma unroll
    for (int i = 0; i < 4; i++) {
        float2 t = __half22float2(acc2[i]);
        acc[2 * i] = t.x; acc[2 * i + 1] = t.y;
    }

    float4 ba = *(const float4*)(b1 + f0);
    float4 bb = *(const float4*)(b1 + f0 + 4);
    float h[8];
    h[0] = fmaxf(fmaf(d, acc[0], ba.x), 0.0f);
    h[1] = fmaxf(fmaf(d, acc[1], ba.y), 0.0f);
    h[2] = fmaxf(fmaf(d, acc[2], ba.z), 0.0f);
    h[3] = fmaxf(fmaf(d, acc[3], ba.w), 0.0f);
    h[4] = fmaxf(fmaf(d, acc[4], bb.x), 0.0f);
    h[5] = fmaxf(fmaf(d, acc[5], bb.y), 0.0f);
    h[6] = fmaxf(fmaf(d, acc[6], bb.z), 0.0f);
    h[7] = fmaxf(fmaf(d, acc[7], bb.w), 0.0f);

    const int cb = (g == 0) ? 0 : (g == 1) ? 3 : (g == 2) ? 6 : 8;
    const int nc = (g < 2) ? 3 : 2;
    float p[3];
    #pragma unroll
    for (int ci = 0; ci < 3; ci++) {
        if (ci < nc) {
            int c = cb + ci;
            float4 wa = *(const float4*)(W2T + c * IN_F + f0);
            float4 wb = *(const float4*)(W2T + c * IN_F + f0 + 4);
            float t = fmaf(h[0], wa.x, fmaf(h[1], wa.y, fmaf(h[2], wa.z, h[3] * wa.w)));
            t = fmaf(h[4], wb.x, fmaf(h[5], wb.y, fmaf(h[6], wb.z, fmaf(h[7], wb.w, t))));
            #pragma unroll
            for (int off = 1; off < 16; off <<= 1) t += __shfl_xor(t, off, 64);
            p[ci] = t;
        }
    }
    if (l16 == 0) {
        __half* o = h2h + (size_t)node * H2P + cb;
        for (int ci = 0; ci < nc; ci++) o[ci] = __float2half(d * p[ci]);
    }
}

// ------- agg2: maskless padded gather (32B rows, 8 lanes/node) + softmax -----
__global__ __launch_bounds__(256) void k_agg2(const __half* __restrict__ h2h,
                                              const int2* __restrict__ rowinfo,
                                              const int* __restrict__ csr,
                                              const float* __restrict__ dis,
                                              const float* __restrict__ b2,
                                              float* __restrict__ out,
                                              int N) {
    int t = blockIdx.x * 256 + threadIdx.x;
    int node = t >> 3;
    if (node >= N) return;
    int o = t & 7;
    int q = o & 1;          // which 8-half chunk of the 16-half row
    int eg = o >> 1;        // edge group 0..3
    const int base = q * 8;
    const __half2 hz = __half2half2(__float2half(0.0f));

    __half2 a2[4] = {hz, hz, hz, hz};
    if (eg == 0) {          // self term
        float4 r = *(const float4*)(h2h + (size_t)node * H2P + base);
        const __half2* hh = (const __half2*)&r;
        a2[0] = hh[0]; a2[1] = hh[1]; a2[2] = hh[2]; a2[3] = hh[3];
    }
    const int2 ri = rowinfo[node];
    const int end = ri.x + ri.y;
    for (int j0 = ri.x + 4 * eg; j0 < end; j0 += 16) {
        int4a cv = *(const int4a*)(csr + j0);
        float4 r0 = *(const float4*)(h2h + (size_t)cv[0] * H2P + base);
        float4 r1 = *(const float4*)(h2h + (size_t)cv[1] * H2P + base);
        float4 r2 = *(const float4*)(h2h + (size_t)cv[2] * H2P + base);
        float4 r3 = *(const float4*)(h2h + (size_t)cv[3] * H2P + base);
        const __half2* h0 = (const __half2*)&r0;
        const __half2* h1 = (const __half2*)&r1;
        const __half2* h2 = (const __half2*)&r2;
        const __half2* h3 = (const __half2*)&r3;
        #pragma unroll
        for (int i = 0; i < 4; i++) {
            a2[i] = __hadd2(a2[i], h0[i]);
            a2[i] = __hadd2(a2[i], h1[i]);
            a2[i] = __hadd2(a2[i], h2[i]);
            a2[i] = __hadd2(a2[i], h3[i]);
        }
    }

    // merge the 4 edge-groups (masks 2 and 4 stay inside the 8-lane octet)
    #pragma unroll
    for (int i = 0; i < 4; i++) {
        a2[i] = __hadd2(a2[i], shfl_xor_h2(a2[i], 2));
        a2[i] = __hadd2(a2[i], shfl_xor_h2(a2[i], 4));
    }

    float a[8];
    #pragma unroll
    for (int i = 0; i < 4; i++) {
        float2 tt = __half22float2(a2[i]);
        a[2 * i] = tt.x; a[2 * i + 1] = tt.y;
    }

    const float d = dis[node];
    float vv[8];
    #pragma unroll
    for (int i = 0; i < 8; i++) {
        int f = base + i;
        vv[i] = (f < NC) ? fmaf(d, a[i], b2[f]) : -1e30f;
    }
    float m = vv[0];
    #pragma unroll
    for (int i = 1; i < 8; i++) m = fmaxf(m, vv[i]);
    m = fmaxf(m, __shfl_xor(m, 1, 64));
    float e[8];
    float s = 0.0f;
    #pragma unroll
    for (int i = 0; i < 8; i++) { e[i] = (base + i < NC) ? expf(vv[i] - m) : 0.0f; s += e[i]; }
    s += __shfl_xor(s, 1, 64);
    float inv = 1.0f / s;

    float* op = out + (size_t)node * NC;
    if (o == 0) {
        *(float2*)(op + 0) = make_float2(e[0] * inv, e[1] * inv);
        *(float2*)(op + 2) = make_float2(e[2] * inv, e[3] * inv);
        *(float2*)(op + 4) = make_float2(e[4] * inv, e[5] * inv);
        *(float2*)(op + 6) = make_float2(e[6] * inv, e[7] * inv);
    } else if (o == 1) {
        *(float2*)(op + 8) = make_float2(e[0] * inv, e[1] * inv);
    }
}

extern "C" void kernel_launch(void* const* d_in, const int* in_sizes, int n_in,
                              void* d_out, int out_size, void* d_ws, size_t ws_size,
                              hipStream_t stream) {
    const float* x  = (const float*)d_in[0];
    const int*   ei = (const int*)d_in[1];
    const float* W1 = (const float*)d_in[2];
    const float* b1 = (const float*)d_in[3];
    const float* W2 = (const float*)d_in[4];
    const float* b2 = (const float*)d_in[5];
    float* out = (float*)d_out;

    const int N = in_sizes[0] / IN_F;   // 100000
    const int E = in_sizes[1] / 2;      // 1600000
    const int* esrc = ei;
    const int* edst = ei + E;
    const int nbin = (N + NPB - 1) / NPB;       // 782
    const int NBG  = (N + 127) / 128;           // 782 GEMM tiles
    const int NBB  = (E + EPB - 1) / EPB;       // 391 bin blocks

    char* ws = (char*)d_ws;
    int2*   rowinfo = (int2*)(ws);                          // 800 KB
    float*  dis     = (float*)(ws + 0x100000);              // 400 KB
    int*    deg     = (int*)(ws + 0x180000);                // 400 KB
    int*    bcnt    = (int*)(ws + 0x1E2000);                // 3.1 KB
    __half* WT      = (__half*)(ws + 0x1F0000);             // 32 KB
    float*  W2T     = (float*)(ws + 0x1F8000);              // 5 KB
    unsigned int* binned = (unsigned int*)(ws + 0x200000);  // 8.0 MB
    int*    csr     = (int*)(ws + 0xA00000);                // 9.2 MB (padded, bin-strided)
    __half* hsh     = (__half*)(ws + 0x1400000);            // 25.6 MB (+ sentinel row N)
    __half* h2h     = (__half*)(ws + 0x2D00000);            // 3.2 MB (+ sentinel row N)

    // zero deg + bcnt in one shot (contiguous region)
    hipMemsetAsync(deg, 0, 0x62000 + (size_t)nbin * sizeof(int), stream);

    k_prep <<<400, 1024, 0, stream>>>(edst, deg, W1, WT, W2, W2T, hsh, h2h, E, N);
    k_work <<<NBG + NBB, 1024, 0, stream>>>(esrc, edst, bcnt, binned, x, WT, deg, dis, hsh,
                                            E, nbin, N, NBG);
    k_place<<<nbin, 256, 0, stream>>>(bcnt, binned, deg, rowinfo, csr, N);
    k_agg1 <<<(N + 3) / 4, 256, 0, stream>>>(hsh, rowinfo, csr, dis, b1, W2T, h2h, N);
    k_agg2 <<<(int)(((size_t)N * 8 + 255) / 256), 256, 0, stream>>>(h2h, rowinfo, csr, dis, b2, out, N);
}

// Round 3
// 230.004 us; speedup vs baseline: 1.2014x; 1.2014x over previous
//
#include <hip/hip_runtime.h>
#include <hip/hip_fp16.h>

#define IN_F 128
#define HID  128
#define NC   10
#define H2P  16     // h2 row stride in HALVES (32 B)
#define NPB  128    // nodes per bin (bin = dst>>7, local = dst&127)
#define NBMAX 784   // max bins (N=100000 -> 782)
#define BCAP 2560   // per-bin edge capacity (mean 2046, +11 sigma)
#define CAPP 2944   // per-bin PADDED csr capacity: BCAP + NPB*3 (each node padded to x4)
#define EPB  4096   // edges per k_bin block (1024 thr x 4) -> 391 blocks
#define LDW  136    // padded LDS row stride in halves (272B -> lane-bank stride 4, ~2-way)

typedef _Float16 f16x8 __attribute__((ext_vector_type(8)));
typedef float f32x4 __attribute__((ext_vector_type(4)));
typedef int int4a __attribute__((ext_vector_type(4), aligned(4)));  // 4B-aligned vec4

__device__ inline __half2 shfl_xor_h2(__half2 v, int mask) {
    int i = __shfl_xor(*reinterpret_cast<int*>(&v), mask, 64);
    return *reinterpret_cast<__half2*>(&i);
}

// ------- phase A: bin edges by dst>>7, packed (dl<<17)|src; blk0 preps WT/W2T -
__global__ __launch_bounds__(1024) void k_bin(const int* __restrict__ src,
                                              const int* __restrict__ dst,
                                              int* __restrict__ bcnt,
                                              unsigned int* __restrict__ binned,
                                              const float* __restrict__ W1,
                                              __half* __restrict__ WT,
                                              const float* __restrict__ W2,
                                              float* __restrict__ W2T,
                                              int E, int nbin) {
    __shared__ int hist[NBMAX];
    __shared__ int base[NBMAX];
    __shared__ int lcur[NBMAX];
    const int tid = threadIdx.x;

    if (blockIdx.x == 0) {   // WT[n][k] = fp16(W1[k][n]); W2T[c][f] = W2[f][c]
        for (int i = tid; i < IN_F * HID; i += 1024) {
            int k = i >> 7, n = i & 127;
            WT[n * IN_F + k] = __float2half(W1[k * HID + n]);
        }
        for (int i = tid; i < NC * IN_F; i += 1024)
            W2T[i] = W2[(i & 127) * NC + (i >> 7)];
    }

    for (int b = tid; b < nbin; b += 1024) { hist[b] = 0; lcur[b] = 0; }
    __syncthreads();

    const int e0 = blockIdx.x * EPB + tid;
    int d[4];
    #pragma unroll
    for (int u = 0; u < 4; u++) {
        int e = e0 + u * 1024;
        d[u] = (e < E) ? dst[e] : -1;
        if (d[u] >= 0) atomicAdd(&hist[d[u] >> 7], 1);
    }
    __syncthreads();
    for (int b = tid; b < nbin; b += 1024) {
        int h = hist[b];
        base[b] = h ? atomicAdd(&bcnt[b], h) : 0;
    }
    __syncthreads();
    #pragma unroll
    for (int u = 0; u < 4; u++) {
        int e = e0 + u * 1024;
        if (e < E) {
            int dd = d[u];
            int b = dd >> 7;
            int s = src[e];
            int o = base[b] + atomicAdd(&lcur[b], 1);
            if (o < BCAP)
                binned[(size_t)b * BCAP + o] = ((unsigned)(dd & 127) << 17) | (unsigned)s;
        }
    }
}

// ------- phase B (fused): per-bin hist/scan -> padded CSR (bin-strided, each
// node's list padded to x4 with sentinel src=N), rowinfo=(beg,cnt4), dis;
// then MFMA GEMM1 over the bin's 128 rows: hsh = fp16(dis[row] * (X @ W1)).
// LDS tiles padded to LDW=136 halves: MFMA ds_read_b128 goes 16-way -> ~2-way.
__global__ __launch_bounds__(256) void k_pg(const int* __restrict__ bcnt,
                                            const unsigned int* __restrict__ binned,
                                            int2* __restrict__ rowinfo,
                                            float* __restrict__ dis,
                                            int* __restrict__ csr,
                                            const float* __restrict__ X,
                                            const __half* __restrict__ WT,
                                            __half* __restrict__ hsh,
                                            __half* __restrict__ h2h,
                                            int N) {
    __shared__ int h[NPB];
    __shared__ int lb[NPB];
    __shared__ int cur[NPB];
    __shared__ float sdis[NPB];
    __shared__ _Float16 sX[32 * LDW];
    __shared__ _Float16 sW[128 * LDW];
    const int b = blockIdx.x;
    const int tid = threadIdx.x;

    if (tid < NPB) h[tid] = 0;
    __syncthreads();

    const int m = min(bcnt[b], BCAP);
    const unsigned int* p = binned + (size_t)b * BCAP;
    for (int i = tid; i < m; i += 256) atomicAdd(&h[p[i] >> 17], 1);
    __syncthreads();

    int myh = 0, cnt4 = 0;
    if (tid < NPB) { myh = h[tid]; cnt4 = (myh + 3) & ~3; lb[tid] = cnt4; }
    __syncthreads();
    #pragma unroll
    for (int off = 1; off < NPB; off <<= 1) {
        int t = (tid < NPB && tid >= off) ? lb[tid - off] : 0;
        __syncthreads();
        if (tid < NPB) lb[tid] += t;
        __syncthreads();
    }
    int ex = 0;
    if (tid < NPB) {
        ex = lb[tid] - cnt4;
        int node = b * NPB + tid;
        if (node < N) {
            rowinfo[node] = make_int2(b * CAPP + ex, cnt4);
            float dd = rsqrtf(1.0f + (float)myh);
            dis[node] = dd;
            sdis[tid] = dd;
        }
        lb[tid] = ex;     // exclusive offsets for scatter
        cur[tid] = 0;
    }
    __syncthreads();
    for (int i = tid; i < m; i += 256) {
        unsigned v = p[i];
        int dl = v >> 17;
        int r = atomicAdd(&cur[dl], 1);
        csr[b * CAPP + lb[dl] + r] = (int)(v & 0x1FFFF);
    }
    if (tid < NPB) {        // pad tail of each node's list with sentinel N
        for (int k = myh; k < cnt4; k++) csr[b * CAPP + ex + k] = N;
    }
    if (b == 0) {           // zero rows for the sentinel node
        f16x8 z = {0, 0, 0, 0, 0, 0, 0, 0};
        if (tid < 16) *(f16x8*)(hsh + (size_t)N * HID + tid * 8) = z;
        if (tid < 2)  *(f16x8*)(h2h + (size_t)N * H2P + tid * 8) = z;
    }

    // ---- GEMM1 phase: 4 tiles of 32 rows over this bin ----
    {
        int n = tid >> 1, part = tid & 1;
        const f16x8* srcp = (const f16x8*)(WT + n * IN_F + part * 64);
        f16x8* dstp = (f16x8*)(sW + n * LDW + part * 64);
        #pragma unroll
        for (int c = 0; c < 8; c++) dstp[c] = srcp[c];
    }
    const int wave = tid >> 6;
    const int lane = tid & 63;
    const int quad = lane >> 4;
    const int l16 = lane & 15;
    const int nbase = wave * 32;

    for (int tdx = 0; tdx < 4; tdx++) {
        int row0 = b * NPB + tdx * 32;
        if (row0 >= N) break;
        __syncthreads();   // prev tile's sX readers done; first iter: sW/sdis ready
        {
            int r = tid >> 3;
            int k0 = (tid & 7) * 16;
            const float* sp = X + (size_t)(row0 + r) * IN_F + k0;
            float4 f0 = *(const float4*)(sp);
            float4 f1 = *(const float4*)(sp + 4);
            float4 f2 = *(const float4*)(sp + 8);
            float4 f3 = *(const float4*)(sp + 12);
            f16x8 h0, h1;
            h0[0] = (_Float16)f0.x; h0[1] = (_Float16)f0.y;
            h0[2] = (_Float16)f0.z; h0[3] = (_Float16)f0.w;
            h0[4] = (_Float16)f1.x; h0[5] = (_Float16)f1.y;
            h0[6] = (_Float16)f1.z; h0[7] = (_Float16)f1.w;
            h1[0] = (_Float16)f2.x; h1[1] = (_Float16)f2.y;
            h1[2] = (_Float16)f2.z; h1[3] = (_Float16)f2.w;
            h1[4] = (_Float16)f3.x; h1[5] = (_Float16)f3.y;
            h1[6] = (_Float16)f3.z; h1[7] = (_Float16)f3.w;
            *(f16x8*)(sX + r * LDW + k0) = h0;
            *(f16x8*)(sX + r * LDW + k0 + 8) = h1;
        }
        __syncthreads();

        f32x4 acc00 = {0,0,0,0}, acc01 = {0,0,0,0}, acc10 = {0,0,0,0}, acc11 = {0,0,0,0};
        #pragma unroll
        for (int kc = 0; kc < 4; kc++) {
            const int koff = kc * 32 + quad * 8;
            f16x8 a0 = *(const f16x8*)(sX + l16 * LDW + koff);
            f16x8 a1 = *(const f16x8*)(sX + (16 + l16) * LDW + koff);
            f16x8 b0 = *(const f16x8*)(sW + (nbase + l16) * LDW + koff);
            f16x8 b1 = *(const f16x8*)(sW + (nbase + 16 + l16) * LDW + koff);
            acc00 = __builtin_amdgcn_mfma_f32_16x16x32_f16(a0, b0, acc00, 0, 0, 0);
            acc01 = __builtin_amdgcn_mfma_f32_16x16x32_f16(a0, b1, acc01, 0, 0, 0);
            acc10 = __builtin_amdgcn_mfma_f32_16x16x32_f16(a1, b0, acc10, 0, 0, 0);
            acc11 = __builtin_amdgcn_mfma_f32_16x16x32_f16(a1, b1, acc11, 0, 0, 0);
        }
        #pragma unroll
        for (int r = 0; r < 4; r++) {
            {
                int lr = tdx * 32 + quad * 4 + r;
                float d = sdis[lr];
                __half* o = hsh + (size_t)(b * NPB + lr) * HID + nbase + l16;
                o[0]  = __float2half(acc00[r] * d);
                o[16] = __float2half(acc01[r] * d);
            }
            {
                int lr = tdx * 32 + 16 + quad * 4 + r;
                float d = sdis[lr];
                __half* o = hsh + (size_t)(b * NPB + lr) * HID + nbase + l16;
                o[0]  = __float2half(acc10[r] * d);
                o[16] = __float2half(acc11[r] * d);
            }
        }
    }
}

// ------- agg1: maskless padded gather (pre-scaled rows) + bias/ReLU + GEMM2 --
// No LDS, no __syncthreads (W2T from global, L1-hot). csr prefetched one round
// ahead so the csr->rows dependent chain pipelines across rounds.
__global__ __launch_bounds__(256) void k_agg1(const __half* __restrict__ hsh,
                                              const int2* __restrict__ rowinfo,
                                              const int* __restrict__ csr,
                                              const float* __restrict__ dis,
                                              const float* __restrict__ b1,
                                              const float* __restrict__ W2T,
                                              __half* __restrict__ h2h,
                                              int N) {
    const int node = blockIdx.x * 4 + (threadIdx.x >> 6);
    if (node >= N) return;
    const int lane = threadIdx.x & 63;
    const int g   = lane >> 4;
    const int l16 = lane & 15;
    const int f0  = l16 * 8;       // 8 halves per lane
    const __half2 hz = __half2half2(__float2half(0.0f));

    const int2 ri = rowinfo[node];
    const int beg = ri.x, end = ri.x + ri.y;
    const float d = dis[node];

    __half2 acc2[4] = {hz, hz, hz, hz};
    if (g == 0) {   // self term (hsh pre-scaled by dis[src])
        float4 r = *(const float4*)(hsh + (size_t)node * HID + f0);
        const __half2* hh = (const __half2*)&r;
        acc2[0] = hh[0]; acc2[1] = hh[1]; acc2[2] = hh[2]; acc2[3] = hh[3];
    }

    int j0 = beg + 4 * g;
    if (j0 < end) {
        int4a cv = *(const int4a*)(csr + j0);
        while (true) {
            const int jn = j0 + 16;
            const bool more = (jn < end);
            int4a cvn = cv;
            if (more) cvn = *(const int4a*)(csr + jn);
            float4 r0 = *(const float4*)(hsh + (size_t)cv[0] * HID + f0);
            float4 r1 = *(const float4*)(hsh + (size_t)cv[1] * HID + f0);
            float4 r2 = *(const float4*)(hsh + (size_t)cv[2] * HID + f0);
            float4 r3 = *(const float4*)(hsh + (size_t)cv[3] * HID + f0);
            const __half2* h0 = (const __half2*)&r0;
            const __half2* h1 = (const __half2*)&r1;
            const __half2* h2 = (const __half2*)&r2;
            const __half2* h3 = (const __half2*)&r3;
            #pragma unroll
            for (int i = 0; i < 4; i++) {
                acc2[i] = __hadd2(acc2[i], h0[i]);
                acc2[i] = __hadd2(acc2[i], h1[i]);
                acc2[i] = __hadd2(acc2[i], h2[i]);
                acc2[i] = __hadd2(acc2[i], h3[i]);
            }
            if (!more) break;
            cv = cvn; j0 = jn;
        }
    }

    // merge the 4 sub-groups, then widen
    #pragma unroll
    for (int i = 0; i < 4; i++) {
        acc2[i] = __hadd2(acc2[i], shfl_xor_h2(acc2[i], 16));
        acc2[i] = __hadd2(acc2[i], shfl_xor_h2(acc2[i], 32));
    }
    float acc[8];
    #pragma unroll
    for (int i = 0; i < 4; i++) {
        float2 t = __half22float2(acc2[i]);
        acc[2 * i] = t.x; acc[2 * i + 1] = t.y;
    }

    float4 ba = *(const float4*)(b1 + f0);
    float4 bb = *(const float4*)(b1 + f0 + 4);
    float h[8];
    h[0] = fmaxf(fmaf(d, acc[0], ba.x), 0.0f);
    h[1] = fmaxf(fmaf(d, acc[1], ba.y), 0.0f);
    h[2] = fmaxf(fmaf(d, acc[2], ba.z), 0.0f);
    h[3] = fmaxf(fmaf(d, acc[3], ba.w), 0.0f);
    h[4] = fmaxf(fmaf(d, acc[4], bb.x), 0.0f);
    h[5] = fmaxf(fmaf(d, acc[5], bb.y), 0.0f);
    h[6] = fmaxf(fmaf(d, acc[6], bb.z), 0.0f);
    h[7] = fmaxf(fmaf(d, acc[7], bb.w), 0.0f);

    const int cb = (g == 0) ? 0 : (g == 1) ? 3 : (g == 2) ? 6 : 8;
    const int nc = (g < 2) ? 3 : 2;
    float p[3];
    #pragma unroll
    for (int ci = 0; ci < 3; ci++) {
        if (ci < nc) {
            int c = cb + ci;
            float4 wa = *(const float4*)(W2T + c * IN_F + f0);
            float4 wb = *(const float4*)(W2T + c * IN_F + f0 + 4);
            float t = fmaf(h[0], wa.x, fmaf(h[1], wa.y, fmaf(h[2], wa.z, h[3] * wa.w)));
            t = fmaf(h[4], wb.x, fmaf(h[5], wb.y, fmaf(h[6], wb.z, fmaf(h[7], wb.w, t))));
            #pragma unroll
            for (int off = 1; off < 16; off <<= 1) t += __shfl_xor(t, off, 64);
            p[ci] = t;
        }
    }
    if (l16 == 0) {
        __half* o = h2h + (size_t)node * H2P + cb;
        for (int ci = 0; ci < nc; ci++) o[ci] = __float2half(d * p[ci]);
    }
}

// ------- agg2: maskless padded gather (32B rows, 8 lanes/node) + softmax -----
__global__ __launch_bounds__(256) void k_agg2(const __half* __restrict__ h2h,
                                              const int2* __restrict__ rowinfo,
                                              const int* __restrict__ csr,
                                              const float* __restrict__ dis,
                                              const float* __restrict__ b2,
                                              float* __restrict__ out,
                                              int N) {
    int t = blockIdx.x * 256 + threadIdx.x;
    int node = t >> 3;
    if (node >= N) return;
    int o = t & 7;
    int q = o & 1;          // which 8-half chunk of the 16-half row
    int eg = o >> 1;        // edge group 0..3
    const int base = q * 8;
    const __half2 hz = __half2half2(__float2half(0.0f));

    __half2 a2[4] = {hz, hz, hz, hz};
    if (eg == 0) {          // self term
        float4 r = *(const float4*)(h2h + (size_t)node * H2P + base);
        const __half2* hh = (const __half2*)&r;
        a2[0] = hh[0]; a2[1] = hh[1]; a2[2] = hh[2]; a2[3] = hh[3];
    }
    const int2 ri = rowinfo[node];
    const int end = ri.x + ri.y;
    for (int j0 = ri.x + 4 * eg; j0 < end; j0 += 16) {
        int4a cv = *(const int4a*)(csr + j0);
        float4 r0 = *(const float4*)(h2h + (size_t)cv[0] * H2P + base);
        float4 r1 = *(const float4*)(h2h + (size_t)cv[1] * H2P + base);
        float4 r2 = *(const float4*)(h2h + (size_t)cv[2] * H2P + base);
        float4 r3 = *(const float4*)(h2h + (size_t)cv[3] * H2P + base);
        const __half2* h0 = (const __half2*)&r0;
        const __half2* h1 = (const __half2*)&r1;
        const __half2* h2 = (const __half2*)&r2;
        const __half2* h3 = (const __half2*)&r3;
        #pragma unroll
        for (int i = 0; i < 4; i++) {
            a2[i] = __hadd2(a2[i], h0[i]);
            a2[i] = __hadd2(a2[i], h1[i]);
            a2[i] = __hadd2(a2[i], h2[i]);
            a2[i] = __hadd2(a2[i], h3[i]);
        }
    }

    // merge the 4 edge-groups (masks 2 and 4 stay inside the 8-lane octet)
    #pragma unroll
    for (int i = 0; i < 4; i++) {
        a2[i] = __hadd2(a2[i], shfl_xor_h2(a2[i], 2));
        a2[i] = __hadd2(a2[i], shfl_xor_h2(a2[i], 4));
    }

    float a[8];
    #pragma unroll
    for (int i = 0; i < 4; i++) {
        float2 tt = __half22float2(a2[i]);
        a[2 * i] = tt.x; a[2 * i + 1] = tt.y;
    }

    const float d = dis[node];
    float vv[8];
    #pragma unroll
    for (int i = 0; i < 8; i++) {
        int f = base + i;
        vv[i] = (f < NC) ? fmaf(d, a[i], b2[f]) : -1e30f;
    }
    float m = vv[0];
    #pragma unroll
    for (int i = 1; i < 8; i++) m = fmaxf(m, vv[i]);
    m = fmaxf(m, __shfl_xor(m, 1, 64));
    float e[8];
    float s = 0.0f;
    #pragma unroll
    for (int i = 0; i < 8; i++) { e[i] = (base + i < NC) ? expf(vv[i] - m) : 0.0f; s += e[i]; }
    s += __shfl_xor(s, 1, 64);
    float inv = 1.0f / s;

    float* op = out + (size_t)node * NC;
    if (o == 0) {
        *(float2*)(op + 0) = make_float2(e[0] * inv, e[1] * inv);
        *(float2*)(op + 2) = make_float2(e[2] * inv, e[3] * inv);
        *(float2*)(op + 4) = make_float2(e[4] * inv, e[5] * inv);
        *(float2*)(op + 6) = make_float2(e[6] * inv, e[7] * inv);
    } else if (o == 1) {
        *(float2*)(op + 8) = make_float2(e[0] * inv, e[1] * inv);
    }
}

extern "C" void kernel_launch(void* const* d_in, const int* in_sizes, int n_in,
                              void* d_out, int out_size, void* d_ws, size_t ws_size,
                              hipStream_t stream) {
    const float* x  = (const float*)d_in[0];
    const int*   ei = (const int*)d_in[1];
    const float* W1 = (const float*)d_in[2];
    const float* b1 = (const float*)d_in[3];
    const float* W2 = (const float*)d_in[4];
    const float* b2 = (const float*)d_in[5];
    float* out = (float*)d_out;

    const int N = in_sizes[0] / IN_F;   // 100000
    const int E = in_sizes[1] / 2;      // 1600000
    const int* esrc = ei;
    const int* edst = ei + E;
    const int nbin = (N + NPB - 1) / NPB;  // 782

    char* ws = (char*)d_ws;
    int2*   rowinfo = (int2*)(ws);                          // N*8   = 800 KB
    float*  dis     = (float*)(ws + 0x100000);              // 400 KB
    int*    bcnt    = (int*)(ws + 0x180000);                // 3.1 KB
    __half* WT      = (__half*)(ws + 0x190000);             // 32 KB
    float*  W2T     = (float*)(ws + 0x1A0000);              // 5 KB
    unsigned int* binned = (unsigned int*)(ws + 0x200000);  // 8.0 MB
    int*    csr     = (int*)(ws + 0xA00000);                // 9.2 MB (padded, bin-strided)
    __half* hsh     = (__half*)(ws + 0x1400000);            // 25.6 MB (+ sentinel row N)
    __half* h2h     = (__half*)(ws + 0x2D00000);            // 3.2 MB (+ sentinel row N)

    hipMemsetAsync(bcnt, 0, (size_t)nbin * sizeof(int), stream);

    k_bin <<<(E + EPB - 1) / EPB, 1024, 0, stream>>>(esrc, edst, bcnt, binned, W1, WT, W2, W2T, E, nbin);
    k_pg  <<<nbin, 256, 0, stream>>>(bcnt, binned, rowinfo, dis, csr, x, WT, hsh, h2h, N);
    k_agg1<<<(N + 3) / 4, 256, 0, stream>>>(hsh, rowinfo, csr, dis, b1, W2T, h2h, N);
    k_agg2<<<(int)(((size_t)N * 8 + 255) / 256), 256, 0, stream>>>(h2h, rowinfo, csr, dis, b2, out, N);
}